// Round 4
// baseline (4367.451 us; speedup 1.0000x reference)
//
#include <hip/hip_runtime.h>
#include <cstdint>

#define NB 16384   // batch
#define NM 256     // M
#define NN 1024    // N
#define NITER 16
#define TOPK 50
#define BMROW 16               // batch rows per block
#define NBLKS (NB / BMROW)     // 1024 blocks

typedef __attribute__((ext_vector_type(8))) short short8;   // 8 bf16 = 4 VGPRs
typedef __attribute__((ext_vector_type(4))) float f32x4;

__device__ inline unsigned short f2bf(float x) {            // RNE fp32 -> bf16
    unsigned u = __float_as_uint(x);
    return (unsigned short)((u + 0x7FFFu + ((u >> 16) & 1u)) >> 16);
}
__device__ inline float bf2f(unsigned short h) {
    return __uint_as_float(((unsigned)h) << 16);
}

// ------------- precompute: element-wise split of phi (NM x NN) -------------
__global__ __launch_bounds__(256) void split_phi_kernel(const float* __restrict__ phi,
                                                        unsigned short* __restrict__ h,
                                                        unsigned short* __restrict__ l) {
    int i = blockIdx.x * 256 + threadIdx.x;
    float v = phi[i];
    unsigned short hh = f2bf(v);
    h[i] = hh;
    l[i] = f2bf(v - bf2f(hh));
}

// -------- precompute: W (NM x NN) -> Wt (NN x NM) transposed + split -------
__global__ __launch_bounds__(256) void transpose_split_W(const float* __restrict__ W,
                                                         unsigned short* __restrict__ th,
                                                         unsigned short* __restrict__ tl) {
    __shared__ float tile[32][33];
    int n0 = blockIdx.x * 32;
    int m0 = blockIdx.y * 32;
    int tx = threadIdx.x;   // 0..31
    int ty = threadIdx.y;   // 0..7
    #pragma unroll
    for (int i = 0; i < 32; i += 8)
        tile[ty + i][tx] = W[(size_t)(m0 + ty + i) * NN + n0 + tx];
    __syncthreads();
    #pragma unroll
    for (int i = 0; i < 32; i += 8) {
        float v = tile[tx][ty + i];
        unsigned short hh = f2bf(v);
        size_t idx = (size_t)(n0 + ty + i) * NM + m0 + tx;
        th[idx] = hh;
        tl[idx] = f2bf(v - bf2f(hh));
    }
}

// ---------------- fully fused persistent-iteration kernel ----------------
// One block = 16 batch rows for all 16 iterations. X never touches HBM.
// 80 KB LDS/block -> 2 blocks/CU (16 waves/CU, 4/SIMD).
//   XH [16][1024] bf16 @ 0       row stride 2048B, byte ^= ((row&7)<<4)
//   XL            @ 32768
//   RH [16][256]  bf16 @ 65536   row stride 512B, same swizzle  } overlapped by
//   RL            @ 73728                                        } select scratch
#define XH_OFF 0
#define XL_OFF 32768
#define RH_OFF 65536
#define RL_OFF 73728
#define HSTRIDE 132                      // words/row: 256 bins packed 2/word + pad
#define HIST_WORDS (16 * HSTRIDE)        // 2112 words = 8448 B
#define PREF_OFF (RH_OFF + HIST_WORDS * 4)   // u32[16]
#define RK_OFF (PREF_OFF + 64)               // u32[16]
#define LDS_BYTES 81920

// (512,4): 4 waves/EU min => 128-reg tier. Per-thread state sized to fit it
// WITHOUT spill (round-1/2 lesson: 1.2GB scratch at BMROW=32's 180-reg demand).
__global__ __launch_bounds__(512, 4) void alista_fused(
        const unsigned short* __restrict__ Ph, const unsigned short* __restrict__ Pl,
        const unsigned short* __restrict__ Wth, const unsigned short* __restrict__ Wtl,
        const float* __restrict__ y, const float* __restrict__ gamma,
        const float* __restrict__ theta, float* __restrict__ out) {
    extern __shared__ char lds[];
    const int tid = threadIdx.x;
    const int w = tid >> 6;          // wave 0..7
    const int lane = tid & 63;
    const int qd = lane >> 4;        // quad 0..3
    const int r16 = lane & 15;
    const int gb0 = blockIdx.x * BMROW;
    const unsigned swzA = (unsigned)((r16 & 7) << 4);   // A-frag row swizzle

    // zero X (XH+XL = 65536 B)
    {
        uint32_t* p = (uint32_t*)lds;
        #pragma unroll
        for (int i = 0; i < 32; ++i) p[tid + i * 512] = 0u;
    }
    __syncthreads();

    // gemm1 B (phi rows m = w*32 + {0,16} + r16), 16B per lane per k-step
    const unsigned short* pPh0 = Ph + (size_t)(w * 32 + r16) * NN + qd * 8;
    const unsigned short* pPh1 = pPh0 + 16 * NN;
    const unsigned short* pPl0 = Pl + (size_t)(w * 32 + r16) * NN + qd * 8;
    const unsigned short* pPl1 = pPl0 + 16 * NN;
    // gemm2 B (Wt rows n = w*128 + j*16 + r16)
    const size_t wn0 = (size_t)(w * 128 + r16) * NM + qd * 8;

    // y values this lane needs are identical every iteration: hoist to regs
    float yreg[2][4];
    #pragma unroll
    for (int m = 0; m < 2; ++m)
        #pragma unroll
        for (int r = 0; r < 4; ++r)
            yreg[m][r] = y[(size_t)(gb0 + qd * 4 + r) * NM + (w * 32 + m * 16 + r16)];

    for (int it = 0; it < NITER; ++it) {
        const float gm = gamma[it];
        const float thv = theta[it];

        // ---- GEMM1: Rt[b,m] = sum_n X[b,n]*phi[m,n] - y[b,m]  (K = 1024) ----
        f32x4 acc1[2];
        acc1[0] = (f32x4){0.f, 0.f, 0.f, 0.f};
        acc1[1] = (f32x4){0.f, 0.f, 0.f, 0.f};

        if (it != 0) {   // it==0: X == 0 -> Rt = -y, skip the K loop
            #pragma unroll 4
            for (int k = 0; k < 32; ++k) {
                short8 bh0 = *(const short8*)(pPh0 + k * 32);
                short8 bh1 = *(const short8*)(pPh1 + k * 32);
                short8 bl0 = *(const short8*)(pPl0 + k * 32);
                short8 bl1 = *(const short8*)(pPl1 + k * 32);
                const unsigned mo = ((unsigned)(k * 64 + qd * 16)) ^ swzA;
                short8 ah = *(const short8*)(lds + XH_OFF + r16 * 2048 + mo);
                short8 al = *(const short8*)(lds + XL_OFF + r16 * 2048 + mo);
                acc1[0] = __builtin_amdgcn_mfma_f32_16x16x32_bf16(ah, bh0, acc1[0], 0, 0, 0);
                acc1[0] = __builtin_amdgcn_mfma_f32_16x16x32_bf16(ah, bl0, acc1[0], 0, 0, 0);
                acc1[0] = __builtin_amdgcn_mfma_f32_16x16x32_bf16(al, bh0, acc1[0], 0, 0, 0);
                acc1[1] = __builtin_amdgcn_mfma_f32_16x16x32_bf16(ah, bh1, acc1[1], 0, 0, 0);
                acc1[1] = __builtin_amdgcn_mfma_f32_16x16x32_bf16(ah, bl1, acc1[1], 0, 0, 0);
                acc1[1] = __builtin_amdgcn_mfma_f32_16x16x32_bf16(al, bh1, acc1[1], 0, 0, 0);
            }
        }
        // epilogue: -y, split bf16 hi/lo, store Rt to LDS
        #pragma unroll
        for (int m = 0; m < 2; ++m) {
            const int gmn = w * 32 + m * 16 + r16;
            #pragma unroll
            for (int r = 0; r < 4; ++r) {
                const int b = qd * 4 + r;
                float v = acc1[m][r] - yreg[m][r];
                unsigned short h = f2bf(v);
                const unsigned mb = ((unsigned)(gmn * 2)) ^ ((unsigned)((b & 7) << 4));
                *(unsigned short*)(lds + RH_OFF + b * 512 + mb) = h;
                *(unsigned short*)(lds + RL_OFF + b * 512 + mb) = f2bf(v - bf2f(h));
            }
        }
        __syncthreads();   // Rt visible to all waves

        // ---- GEMM2: acc2[b,n] = sum_m Rt[b,m]*W[m,n]  (K = 256) ----
        f32x4 acc2[8];
        #pragma unroll
        for (int j = 0; j < 8; ++j) acc2[j] = (f32x4){0.f, 0.f, 0.f, 0.f};

        #pragma unroll 2
        for (int k = 0; k < 8; ++k) {
            const unsigned mo = ((unsigned)(k * 64 + qd * 16)) ^ swzA;
            short8 ah = *(const short8*)(lds + RH_OFF + r16 * 512 + mo);
            short8 al = *(const short8*)(lds + RL_OFF + r16 * 512 + mo);
            // consume B in pairs: live B set = 4 short8 (16 VGPR)
            #pragma unroll
            for (int jp = 0; jp < 4; ++jp) {
                const int j0 = 2 * jp, j1 = 2 * jp + 1;
                short8 wh0 = *(const short8*)(Wth + wn0 + j0 * 4096 + k * 32);
                short8 wl0 = *(const short8*)(Wtl + wn0 + j0 * 4096 + k * 32);
                short8 wh1 = *(const short8*)(Wth + wn0 + j1 * 4096 + k * 32);
                short8 wl1 = *(const short8*)(Wtl + wn0 + j1 * 4096 + k * 32);
                acc2[j0] = __builtin_amdgcn_mfma_f32_16x16x32_bf16(ah, wh0, acc2[j0], 0, 0, 0);
                acc2[j0] = __builtin_amdgcn_mfma_f32_16x16x32_bf16(ah, wl0, acc2[j0], 0, 0, 0);
                acc2[j0] = __builtin_amdgcn_mfma_f32_16x16x32_bf16(al, wh0, acc2[j0], 0, 0, 0);
                acc2[j1] = __builtin_amdgcn_mfma_f32_16x16x32_bf16(ah, wh1, acc2[j1], 0, 0, 0);
                acc2[j1] = __builtin_amdgcn_mfma_f32_16x16x32_bf16(ah, wl1, acc2[j1], 0, 0, 0);
                acc2[j1] = __builtin_amdgcn_mfma_f32_16x16x32_bf16(al, wh1, acc2[j1], 0, 0, 0);
            }
        }

        // ---- V = x_old - gamma*acc2 (kept in the acc registers) ----
        #pragma unroll
        for (int j = 0; j < 8; ++j) {
            const int n = w * 128 + j * 16 + r16;
            #pragma unroll
            for (int r = 0; r < 4; ++r) {
                const int b = qd * 4 + r;
                const unsigned nb2 = ((unsigned)(n * 2)) ^ ((unsigned)((b & 7) << 4));
                float xo = bf2f(*(const unsigned short*)(lds + XH_OFF + b * 2048 + nb2)) +
                           bf2f(*(const unsigned short*)(lds + XL_OFF + b * 2048 + nb2));
                acc2[j][r] = xo - gm * acc2[j][r];
            }
        }
        __syncthreads();   // all Rt reads done -> region reusable for select

        // ---- exact per-row 50th-largest |v|: 4-pass radix histogram ----
        // (bits [30:23],[22:15],[14:7],[6:0]; 256 bins packed 2 counts/u32 word)
        uint32_t* hist = (uint32_t*)(lds + RH_OFF);
        uint32_t* prefA = (uint32_t*)(lds + PREF_OFF);
        uint32_t* rkA = (uint32_t*)(lds + RK_OFF);
        #pragma unroll
        for (int i = 0; i < 5; ++i) {
            int idx = tid + i * 512;
            if (idx < HIST_WORDS) hist[idx] = 0u;
        }
        if (tid < 16) { prefA[tid] = 0u; rkA[tid] = TOPK; }
        __syncthreads();

        // One owner quad per row (w<4 only): the scan does RMW on prefA/rkA
        // with no internal barrier -- a duplicate scanner (round-3's w&3) races
        // on rkA and corrupts the threshold.
        const int srow = w * 4 + qd;   // rows 0..15 for w<4
        #pragma unroll
        for (int pass = 0; pass < 4; ++pass) {
            const int s = (pass == 0) ? 23 : (pass == 1) ? 15 : (pass == 2) ? 7 : 0;
            const int sTop = (pass == 0) ? 31 : (pass == 1) ? 23 : (pass == 2) ? 15 : 7;
            const unsigned bmask = (pass == 3) ? 0x7Fu : 0xFFu;
            unsigned prefs[4];
            #pragma unroll
            for (int r = 0; r < 4; ++r) prefs[r] = prefA[qd * 4 + r];
            #pragma unroll
            for (int j = 0; j < 8; ++j)
                #pragma unroll
                for (int r = 0; r < 4; ++r) {
                    unsigned u = __float_as_uint(acc2[j][r]) & 0x7FFFFFFFu;
                    if ((u >> sTop) == (prefs[r] >> sTop)) {
                        unsigned bin = (u >> s) & bmask;
                        atomicAdd(&hist[(qd * 4 + r) * HSTRIDE + (bin >> 1)],
                                  1u << ((bin & 1) * 16));
                    }
                }
            __syncthreads();
            if (w < 4) {
                // suffix-scan 256 bins of row srow across this quad's 16 lanes
                unsigned cnt[16];
                unsigned lsum = 0;
                #pragma unroll
                for (int i = 0; i < 8; ++i) {
                    unsigned wd = hist[srow * HSTRIDE + r16 * 8 + i];
                    cnt[2 * i] = wd & 0xFFFFu;
                    cnt[2 * i + 1] = wd >> 16;
                    lsum += cnt[2 * i] + cnt[2 * i + 1];
                }
                unsigned S = lsum;
                #pragma unroll
                for (int off = 1; off < 16; off <<= 1) {
                    unsigned o = (unsigned)__shfl_down((int)S, off, 16);
                    if (r16 + off < 16) S += o;
                }
                const unsigned rk = rkA[srow];
                const unsigned pOld = prefA[srow];
                unsigned run = S - lsum;   // count in strictly-higher lanes' bins
                #pragma unroll
                for (int i = 15; i >= 0; --i) {
                    unsigned tot = run + cnt[i];
                    if (run < rk && tot >= rk) {   // unique (lane,i) satisfies this
                        prefA[srow] = pOld | (((unsigned)(r16 * 16 + i)) << s);
                        rkA[srow] = rk - run;
                    }
                    run = tot;
                }
            }
            __syncthreads();
            if (pass < 3) {
                #pragma unroll
                for (int i = 0; i < 5; ++i) {
                    int idx = tid + i * 512;
                    if (idx < HIST_WORDS) hist[idx] = 0u;
                }
                __syncthreads();
            }
        }

        // ---- update: soft-threshold + exact top-k passthrough, write X LDS ----
        unsigned Ts[4];
        #pragma unroll
        for (int r = 0; r < 4; ++r) Ts[r] = prefA[qd * 4 + r];
        #pragma unroll
        for (int j = 0; j < 8; ++j) {
            const int n = w * 128 + j * 16 + r16;
            #pragma unroll
            for (int r = 0; r < 4; ++r) {
                const int b = qd * 4 + r;
                const unsigned nb2 = ((unsigned)(n * 2)) ^ ((unsigned)((b & 7) << 4));
                float xo = bf2f(*(const unsigned short*)(lds + XH_OFF + b * 2048 + nb2)) +
                           bf2f(*(const unsigned short*)(lds + XL_OFF + b * 2048 + nb2));
                float v = acc2[j][r];
                float th = thv / (10.0f * fabsf(xo) + 1.0f);   // theta*g(|x|), EPS=0.1
                float st = copysignf(fmaxf(fabsf(v) - th, 0.0f), v);
                unsigned u = __float_as_uint(v) & 0x7FFFFFFFu;
                float outv = (u > Ts[r]) ? v : st;
                unsigned short h = f2bf(outv);
                *(unsigned short*)(lds + XH_OFF + b * 2048 + nb2) = h;
                *(unsigned short*)(lds + XL_OFF + b * 2048 + nb2) = f2bf(outv - bf2f(h));
                if (it == NITER - 1) out[(size_t)(gb0 + b) * NN + n] = outv;
            }
        }
        __syncthreads();   // X updated for next iteration's gemm1
    }
}

__global__ void tail_kernel(float* __restrict__ out) {
    if (threadIdx.x < 32) out[(size_t)NB * NN + threadIdx.x] = 0.0f;
}

extern "C" void kernel_launch(void* const* d_in, const int* in_sizes, int n_in,
                              void* d_out, int out_size, void* d_ws, size_t ws_size,
                              hipStream_t stream) {
    const float* y     = (const float*)d_in[0];
    const float* phi   = (const float*)d_in[1];
    const float* W     = (const float*)d_in[2];
    const float* gamma = (const float*)d_in[3];
    const float* theta = (const float*)d_in[4];
    float* out = (float*)d_out;

    char* ws = (char*)d_ws;
    size_t off = 0;
    unsigned short* Ph  = (unsigned short*)(ws + off); off += (size_t)NM * NN * 2;  // 512KB
    unsigned short* Pl  = (unsigned short*)(ws + off); off += (size_t)NM * NN * 2;
    unsigned short* Wth = (unsigned short*)(ws + off); off += (size_t)NN * NM * 2;
    unsigned short* Wtl = (unsigned short*)(ws + off); off += (size_t)NN * NM * 2;

    static int attr_done = 0;
    if (!attr_done) {
        (void)hipFuncSetAttribute(reinterpret_cast<const void*>(alista_fused),
                                  hipFuncAttributeMaxDynamicSharedMemorySize, LDS_BYTES);
        attr_done = 1;
    }

    split_phi_kernel<<<(NM * NN) / 256, 256, 0, stream>>>(phi, Ph, Pl);
    transpose_split_W<<<dim3(NN / 32, NM / 32), dim3(32, 8), 0, stream>>>(W, Wth, Wtl);
    alista_fused<<<NBLKS, 512, LDS_BYTES, stream>>>(Ph, Pl, Wth, Wtl, y, gamma, theta, out);
    tail_kernel<<<1, 32, 0, stream>>>(out);
}

// Round 5
// 4087.490 us; speedup vs baseline: 1.0685x; 1.0685x over previous
//
#include <hip/hip_runtime.h>
#include <cstdint>

#define NB 16384   // batch
#define NM 256     // M
#define NN 1024    // N
#define NITER 16
#define TOPK 50
#define BMROW 16               // batch rows per block
#define NBLKS (NB / BMROW)     // 1024 blocks

typedef __attribute__((ext_vector_type(8))) short short8;   // 8 bf16 = 4 VGPRs
typedef __attribute__((ext_vector_type(4))) float f32x4;

__device__ inline unsigned short f2bf(float x) {            // RNE fp32 -> bf16
    unsigned u = __float_as_uint(x);
    return (unsigned short)((u + 0x7FFFu + ((u >> 16) & 1u)) >> 16);
}
__device__ inline float bf2f(unsigned short h) {
    return __uint_as_float(((unsigned)h) << 16);
}
// X swizzle: involution on bits 4-6 keyed by row (bits 11-14) and 128B-chunk
// (bits 7-9): conflict-free for BOTH the gemm1 A-frag pattern (16 rows at
// stride 2048) and the row-linear phase-B/D pattern (chunk-per-lane).
__device__ inline unsigned swzX(unsigned byte) {
    return byte ^ ((((byte >> 11) ^ (byte >> 7)) & 7u) << 4);
}
// strip swizzle: row (bits 7-10) into bits 4-6
__device__ inline unsigned swzS(unsigned byte) {
    return byte ^ (((byte >> 7) & 7u) << 4);
}

// ------------- precompute: element-wise split of phi (NM x NN) -------------
__global__ __launch_bounds__(256) void split_phi_kernel(const float* __restrict__ phi,
                                                        unsigned short* __restrict__ h,
                                                        unsigned short* __restrict__ l) {
    int i = blockIdx.x * 256 + threadIdx.x;
    float v = phi[i];
    unsigned short hh = f2bf(v);
    h[i] = hh;
    l[i] = f2bf(v - bf2f(hh));
}

// -------- precompute: W (NM x NN) -> Wt (NN x NM) transposed + split -------
__global__ __launch_bounds__(256) void transpose_split_W(const float* __restrict__ W,
                                                         unsigned short* __restrict__ th,
                                                         unsigned short* __restrict__ tl) {
    __shared__ float tile[32][33];
    int n0 = blockIdx.x * 32;
    int m0 = blockIdx.y * 32;
    int tx = threadIdx.x;   // 0..31
    int ty = threadIdx.y;   // 0..7
    #pragma unroll
    for (int i = 0; i < 32; i += 8)
        tile[ty + i][tx] = W[(size_t)(m0 + ty + i) * NN + n0 + tx];
    __syncthreads();
    #pragma unroll
    for (int i = 0; i < 32; i += 8) {
        float v = tile[tx][ty + i];
        unsigned short hh = f2bf(v);
        size_t idx = (size_t)(n0 + ty + i) * NM + m0 + tx;
        th[idx] = hh;
        tl[idx] = f2bf(v - bf2f(hh));
    }
}

// ---------------- fully fused persistent-iteration kernel ----------------
// One block = 16 batch rows for all 16 iterations. X never leaves LDS.
// 80 KB LDS -> 2 blocks/CU. All X traffic is 16B-vectorized; the MFMA->row
// layout exchange goes through per-wave 2KB strips (barrier-free, in-order DS).
//   XH [16][1024] bf16 @ 0      row stride 2048B, swzX
//   XL            @ 32768
//   R  16 KB      @ 65536       lifetimes: Rt(h 8K,l 8K) -> strips -> hist
#define XH_OFF 0
#define XL_OFF 32768
#define R_OFF  65536
#define RH_OFF R_OFF
#define RL_OFF (R_OFF + 8192)
#define HSTRIDE 132                      // words/row: 256 bins packed 2/word + pad
#define HIST_WORDS (16 * HSTRIDE)        // 2112 words = 8448 B
#define PREF_OFF (R_OFF + 12288)         // u32[16] (written only after strips die)
#define RK_OFF (PREF_OFF + 64)           // u32[16]
#define LDS_BYTES 81920

__global__ __launch_bounds__(512, 4) void alista_fused(
        const unsigned short* __restrict__ Ph, const unsigned short* __restrict__ Pl,
        const unsigned short* __restrict__ Wth, const unsigned short* __restrict__ Wtl,
        const float* __restrict__ y, const float* __restrict__ gamma,
        const float* __restrict__ theta, float* __restrict__ out) {
    extern __shared__ char lds[];
    const int tid = threadIdx.x;
    const int w = tid >> 6;          // wave 0..7
    const int lane = tid & 63;
    const int qd = lane >> 4;        // quad 0..3
    const int r16 = lane & 15;
    const int lrow = lane >> 2;      // row this lane owns in phase B/D (0..15)
    const int lq = lane & 3;         // col-quarter within wave's 128 cols
    const int gb0 = blockIdx.x * BMROW;

    // zero X (XH+XL = 65536 B)
    {
        uint32_t* p = (uint32_t*)lds;
        #pragma unroll
        for (int i = 0; i < 32; ++i) p[tid + i * 512] = 0u;
    }
    __syncthreads();

    // gemm1 B (phi rows m = w*32 + {0,16} + r16), 16B per lane per k-step
    const unsigned short* pPh0 = Ph + (size_t)(w * 32 + r16) * NN + qd * 8;
    const unsigned short* pPh1 = pPh0 + 16 * NN;
    const unsigned short* pPl0 = Pl + (size_t)(w * 32 + r16) * NN + qd * 8;
    const unsigned short* pPl1 = pPl0 + 16 * NN;
    // gemm2 B (Wt rows n = w*128 + j*16 + r16)
    const size_t wn0 = (size_t)(w * 128 + r16) * NM + qd * 8;

    // y values this lane needs are identical every iteration: hoist to regs
    float yreg[2][4];
    #pragma unroll
    for (int m = 0; m < 2; ++m)
        #pragma unroll
        for (int r = 0; r < 4; ++r)
            yreg[m][r] = y[(size_t)(gb0 + qd * 4 + r) * NM + (w * 32 + m * 16 + r16)];

    uint32_t* hist = (uint32_t*)(lds + R_OFF);
    uint32_t* prefA = (uint32_t*)(lds + PREF_OFF);
    uint32_t* rkA = (uint32_t*)(lds + RK_OFF);
    char* strip = lds + R_OFF + w * 2048;      // per-wave exchange strip
    const unsigned xbase = (unsigned)(lrow * 2048 + w * 256 + lq * 64);

    for (int it = 0; it < NITER; ++it) {
        const float gm = gamma[it];
        const float thv = theta[it];

        // ---- GEMM1: Rt[b,m] = sum_n X[b,n]*phi[m,n] - y[b,m]  (K = 1024) ----
        f32x4 acc1[2];
        acc1[0] = (f32x4){0.f, 0.f, 0.f, 0.f};
        acc1[1] = (f32x4){0.f, 0.f, 0.f, 0.f};

        if (it != 0) {   // it==0: X == 0 -> Rt = -y, skip the K loop
            #pragma unroll 4
            for (int k = 0; k < 32; ++k) {
                short8 bh0 = *(const short8*)(pPh0 + k * 32);
                short8 bh1 = *(const short8*)(pPh1 + k * 32);
                short8 bl0 = *(const short8*)(pPl0 + k * 32);
                short8 bl1 = *(const short8*)(pPl1 + k * 32);
                const unsigned xb = swzX((unsigned)(r16 * 2048 + k * 64 + qd * 16));
                short8 ah = *(const short8*)(lds + XH_OFF + xb);
                short8 al = *(const short8*)(lds + XL_OFF + xb);
                acc1[0] = __builtin_amdgcn_mfma_f32_16x16x32_bf16(ah, bh0, acc1[0], 0, 0, 0);
                acc1[0] = __builtin_amdgcn_mfma_f32_16x16x32_bf16(ah, bl0, acc1[0], 0, 0, 0);
                acc1[0] = __builtin_amdgcn_mfma_f32_16x16x32_bf16(al, bh0, acc1[0], 0, 0, 0);
                acc1[1] = __builtin_amdgcn_mfma_f32_16x16x32_bf16(ah, bh1, acc1[1], 0, 0, 0);
                acc1[1] = __builtin_amdgcn_mfma_f32_16x16x32_bf16(ah, bl1, acc1[1], 0, 0, 0);
                acc1[1] = __builtin_amdgcn_mfma_f32_16x16x32_bf16(al, bh1, acc1[1], 0, 0, 0);
            }
        }
        // epilogue: -y, split bf16 hi/lo, store Rt to LDS (R region)
        #pragma unroll
        for (int m = 0; m < 2; ++m) {
            const int gmn = w * 32 + m * 16 + r16;
            #pragma unroll
            for (int r = 0; r < 4; ++r) {
                const int b = qd * 4 + r;
                float v = acc1[m][r] - yreg[m][r];
                unsigned short h = f2bf(v);
                const unsigned mb = ((unsigned)(gmn * 2)) ^ ((unsigned)((b & 7) << 4));
                *(unsigned short*)(lds + RH_OFF + b * 512 + mb) = h;
                *(unsigned short*)(lds + RL_OFF + b * 512 + mb) = f2bf(v - bf2f(h));
            }
        }
        __syncthreads();   // B1: Rt visible to all waves

        // ---- GEMM2: acc2[b,n] = sum_m Rt[b,m]*W[m,n]  (K = 256) ----
        f32x4 acc2[8];
        #pragma unroll
        for (int j = 0; j < 8; ++j) acc2[j] = (f32x4){0.f, 0.f, 0.f, 0.f};

        #pragma unroll 2
        for (int k = 0; k < 8; ++k) {
            const unsigned mo = ((unsigned)(k * 64 + qd * 16)) ^ ((unsigned)((r16 & 7) << 4));
            short8 ah = *(const short8*)(lds + RH_OFF + r16 * 512 + mo);
            short8 al = *(const short8*)(lds + RL_OFF + r16 * 512 + mo);
            #pragma unroll
            for (int jp = 0; jp < 4; ++jp) {
                const int j0 = 2 * jp, j1 = 2 * jp + 1;
                short8 wh0 = *(const short8*)(Wth + wn0 + j0 * 4096 + k * 32);
                short8 wl0 = *(const short8*)(Wtl + wn0 + j0 * 4096 + k * 32);
                short8 wh1 = *(const short8*)(Wth + wn0 + j1 * 4096 + k * 32);
                short8 wl1 = *(const short8*)(Wtl + wn0 + j1 * 4096 + k * 32);
                acc2[j0] = __builtin_amdgcn_mfma_f32_16x16x32_bf16(ah, wh0, acc2[j0], 0, 0, 0);
                acc2[j0] = __builtin_amdgcn_mfma_f32_16x16x32_bf16(ah, wl0, acc2[j0], 0, 0, 0);
                acc2[j0] = __builtin_amdgcn_mfma_f32_16x16x32_bf16(al, wh0, acc2[j0], 0, 0, 0);
                acc2[j1] = __builtin_amdgcn_mfma_f32_16x16x32_bf16(ah, wh1, acc2[j1], 0, 0, 0);
                acc2[j1] = __builtin_amdgcn_mfma_f32_16x16x32_bf16(ah, wl1, acc2[j1], 0, 0, 0);
                acc2[j1] = __builtin_amdgcn_mfma_f32_16x16x32_bf16(al, wh1, acc2[j1], 0, 0, 0);
            }
        }
        __syncthreads();   // B2: all Rt reads done -> R region free for strips

        // ---- layout exchange: MFMA scatter -> row-linear, intra-wave ----
        // 4 sub-rounds over a private 2KB strip; no barriers (per-wave DS order).
        float v[32];   // after exchange: v[i] = c at (row lrow, col w*128+lq*32+i)
        #pragma unroll
        for (int q = 0; q < 4; ++q) {
            #pragma unroll
            for (int e = 0; e < 2; ++e) {
                const int j = 2 * q + e;
                #pragma unroll
                for (int r = 0; r < 4; ++r) {
                    const int b = qd * 4 + r;
                    const unsigned sb = swzS((unsigned)(b * 128 + e * 64 + r16 * 4));
                    *(float*)(strip + sb) = acc2[j][r];
                }
            }
            if (lq == q) {
                #pragma unroll
                for (int g = 0; g < 8; ++g) {
                    const unsigned rb = swzS((unsigned)(lrow * 128 + g * 16));
                    f32x4 t = *(const f32x4*)(strip + rb);
                    v[g * 4 + 0] = t[0]; v[g * 4 + 1] = t[1];
                    v[g * 4 + 2] = t[2]; v[g * 4 + 3] = t[3];
                }
            }
        }
        __syncthreads();   // B3: strips dead -> R free for hist

        // ---- phase B: v = x_old - gamma*c, xo vectorized from X ----
        #pragma unroll
        for (int g = 0; g < 4; ++g) {
            const unsigned xb = swzX(xbase + g * 16);
            short8 xh = *(const short8*)(lds + XH_OFF + xb);
            short8 xl = *(const short8*)(lds + XL_OFF + xb);
            #pragma unroll
            for (int e2 = 0; e2 < 8; ++e2) {
                float xo = bf2f((unsigned short)xh[e2]) + bf2f((unsigned short)xl[e2]);
                v[g * 8 + e2] = xo - gm * v[g * 8 + e2];
            }
        }

        // ---- exact per-row 50th-largest |v|: 4-pass radix histogram ----
        #pragma unroll
        for (int i = 0; i < 5; ++i) {
            int idx = tid + i * 512;
            if (idx < HIST_WORDS) hist[idx] = 0u;
        }
        if (tid < 16) { prefA[tid] = 0u; rkA[tid] = TOPK; }
        __syncthreads();   // B4

        const int srow = w * 4 + qd;   // row scanned by this quad (w<4 only)
        #pragma unroll
        for (int pass = 0; pass < 4; ++pass) {
            const int s = (pass == 0) ? 23 : (pass == 1) ? 15 : (pass == 2) ? 7 : 0;
            const int sTop = (pass == 0) ? 31 : (pass == 1) ? 23 : (pass == 2) ? 15 : 7;
            const unsigned bmask = (pass == 3) ? 0x7Fu : 0xFFu;
            const unsigned pref = prefA[lrow];
            #pragma unroll
            for (int i = 0; i < 32; ++i) {
                unsigned u = __float_as_uint(v[i]) & 0x7FFFFFFFu;
                if ((u >> sTop) == (pref >> sTop)) {
                    unsigned bin = (u >> s) & bmask;
                    atomicAdd(&hist[lrow * HSTRIDE + (bin >> 1)], 1u << ((bin & 1) * 16));
                }
            }
            __syncthreads();
            if (w < 4) {   // one owner quad per row: scan is RMW on prefA/rkA
                unsigned cnt[16];
                unsigned lsum = 0;
                #pragma unroll
                for (int i = 0; i < 8; ++i) {
                    unsigned wd = hist[srow * HSTRIDE + r16 * 8 + i];
                    cnt[2 * i] = wd & 0xFFFFu;
                    cnt[2 * i + 1] = wd >> 16;
                    lsum += cnt[2 * i] + cnt[2 * i + 1];
                }
                unsigned S = lsum;
                #pragma unroll
                for (int off = 1; off < 16; off <<= 1) {
                    unsigned o = (unsigned)__shfl_down((int)S, off, 16);
                    if (r16 + off < 16) S += o;
                }
                const unsigned rk = rkA[srow];
                const unsigned pOld = prefA[srow];
                unsigned run = S - lsum;
                #pragma unroll
                for (int i = 15; i >= 0; --i) {
                    unsigned tot = run + cnt[i];
                    if (run < rk && tot >= rk) {
                        prefA[srow] = pOld | (((unsigned)(r16 * 16 + i)) << s);
                        rkA[srow] = rk - run;
                    }
                    run = tot;
                }
            }
            __syncthreads();
            if (pass < 3) {
                #pragma unroll
                for (int i = 0; i < 5; ++i) {
                    int idx = tid + i * 512;
                    if (idx < HIST_WORDS) hist[idx] = 0u;
                }
                __syncthreads();
            }
        }

        // ---- phase D: soft-threshold + exact top-k passthrough, vectorized ----
        const unsigned T = prefA[lrow];
        #pragma unroll
        for (int g = 0; g < 4; ++g) {
            const unsigned xb = swzX(xbase + g * 16);
            short8 xh = *(const short8*)(lds + XH_OFF + xb);
            short8 xl = *(const short8*)(lds + XL_OFF + xb);
            short8 nh, nl;
            #pragma unroll
            for (int e2 = 0; e2 < 8; ++e2) {
                const int i = g * 8 + e2;
                float xo = bf2f((unsigned short)xh[e2]) + bf2f((unsigned short)xl[e2]);
                float vv = v[i];
                float th = thv / (10.0f * fabsf(xo) + 1.0f);   // theta*g(|x|), EPS=0.1
                float st = copysignf(fmaxf(fabsf(vv) - th, 0.0f), vv);
                unsigned u = __float_as_uint(vv) & 0x7FFFFFFFu;
                float outv = (u > T) ? vv : st;
                unsigned short h = f2bf(outv);
                nh[e2] = (short)h;
                nl[e2] = (short)f2bf(outv - bf2f(h));
                v[i] = outv;
            }
            *(short8*)(lds + XH_OFF + xb) = nh;
            *(short8*)(lds + XL_OFF + xb) = nl;
        }
        if (it == NITER - 1) {
            const size_t ob = (size_t)(gb0 + lrow) * NN + w * 128 + lq * 32;
            #pragma unroll
            for (int g = 0; g < 8; ++g) {
                float4 o4 = {v[g * 4 + 0], v[g * 4 + 1], v[g * 4 + 2], v[g * 4 + 3]};
                *reinterpret_cast<float4*>(&out[ob + g * 4]) = o4;
            }
        }
        __syncthreads();   // B5: X updated for next iteration's gemm1
    }
}

__global__ void tail_kernel(float* __restrict__ out) {
    if (threadIdx.x < 32) out[(size_t)NB * NN + threadIdx.x] = 0.0f;
}

extern "C" void kernel_launch(void* const* d_in, const int* in_sizes, int n_in,
                              void* d_out, int out_size, void* d_ws, size_t ws_size,
                              hipStream_t stream) {
    const float* y     = (const float*)d_in[0];
    const float* phi   = (const float*)d_in[1];
    const float* W     = (const float*)d_in[2];
    const float* gamma = (const float*)d_in[3];
    const float* theta = (const float*)d_in[4];
    float* out = (float*)d_out;

    char* ws = (char*)d_ws;
    size_t off = 0;
    unsigned short* Ph  = (unsigned short*)(ws + off); off += (size_t)NM * NN * 2;  // 512KB
    unsigned short* Pl  = (unsigned short*)(ws + off); off += (size_t)NM * NN * 2;
    unsigned short* Wth = (unsigned short*)(ws + off); off += (size_t)NN * NM * 2;
    unsigned short* Wtl = (unsigned short*)(ws + off); off += (size_t)NN * NM * 2;

    static int attr_done = 0;
    if (!attr_done) {
        (void)hipFuncSetAttribute(reinterpret_cast<const void*>(alista_fused),
                                  hipFuncAttributeMaxDynamicSharedMemorySize, LDS_BYTES);
        attr_done = 1;
    }

    split_phi_kernel<<<(NM * NN) / 256, 256, 0, stream>>>(phi, Ph, Pl);
    transpose_split_W<<<dim3(NN / 32, NM / 32), dim3(32, 8), 0, stream>>>(W, Wth, Wtl);
    alista_fused<<<NBLKS, 512, LDS_BYTES, stream>>>(Ph, Pl, Wth, Wtl, y, gamma, theta, out);
    tail_kernel<<<1, 32, 0, stream>>>(out);
}

// Round 6
// 3064.238 us; speedup vs baseline: 1.4253x; 1.3339x over previous
//
#include <hip/hip_runtime.h>
#include <cstdint>

#define NB 16384   // batch
#define NM 256     // M
#define NN 1024    // N
#define NITER 16
#define TOPK 50
#define BMROW 16               // batch rows per gemm2_update block
#define NBLKS2 (NB / BMROW)    // 1024 blocks

typedef __attribute__((ext_vector_type(8))) short short8;   // 8 bf16 = 4 VGPRs
typedef __attribute__((ext_vector_type(4))) float f32x4;

__device__ inline unsigned short f2bf(float x) {            // RNE fp32 -> bf16
    unsigned u = __float_as_uint(x);
    return (unsigned short)((u + 0x7FFFu + ((u >> 16) & 1u)) >> 16);
}
__device__ inline float bf2f(unsigned short h) {
    return __uint_as_float(((unsigned)h) << 16);
}
__device__ inline void gload16(const void* g, void* lds_) {  // 16B global -> LDS
    __builtin_amdgcn_global_load_lds(
        (const __attribute__((address_space(1))) unsigned*)g,
        (__attribute__((address_space(3))) unsigned*)lds_, 16, 0, 0);
}
// strip swizzle: row (bits 7-10) into bits 4-6
__device__ inline unsigned swzS(unsigned byte) {
    return byte ^ (((byte >> 7) & 7u) << 4);
}

// ------------- precompute: element-wise split of phi (NM x NN) -------------
__global__ __launch_bounds__(256) void split_phi_kernel(const float* __restrict__ phi,
                                                        unsigned short* __restrict__ h,
                                                        unsigned short* __restrict__ l) {
    int i = blockIdx.x * 256 + threadIdx.x;
    float v = phi[i];
    unsigned short hh = f2bf(v);
    h[i] = hh;
    l[i] = f2bf(v - bf2f(hh));
}

// -------- precompute: W (NM x NN) -> Wt (NN x NM) transposed + split -------
__global__ __launch_bounds__(256) void transpose_split_W(const float* __restrict__ W,
                                                         unsigned short* __restrict__ th,
                                                         unsigned short* __restrict__ tl) {
    __shared__ float tile[32][33];
    int n0 = blockIdx.x * 32;
    int m0 = blockIdx.y * 32;
    int tx = threadIdx.x;   // 0..31
    int ty = threadIdx.y;   // 0..7
    #pragma unroll
    for (int i = 0; i < 32; i += 8)
        tile[ty + i][tx] = W[(size_t)(m0 + ty + i) * NN + n0 + tx];
    __syncthreads();
    #pragma unroll
    for (int i = 0; i < 32; i += 8) {
        float v = tile[tx][ty + i];
        unsigned short hh = f2bf(v);
        size_t idx = (size_t)(n0 + ty + i) * NM + m0 + tx;
        th[idx] = hh;
        tl[idx] = f2bf(v - bf2f(hh));
    }
}

// ---- GEMM1 (round-0 verbatim, proven): Rt(B x NM) = X(B x NN) @ phiT - y ----
#define BM1 128
#define BN1 64
#define BK  32
__global__ __launch_bounds__(256) void gemm1_mfma(const unsigned short* __restrict__ Xh,
                                                  const unsigned short* __restrict__ Xl,
                                                  const unsigned short* __restrict__ Ph,
                                                  const unsigned short* __restrict__ Pl,
                                                  const float* __restrict__ y,
                                                  unsigned short* __restrict__ Rth,
                                                  unsigned short* __restrict__ Rtl) {
    __shared__ unsigned short sAh[BM1 * BK];  // 8KB, row stride 32 elem = 64B
    __shared__ unsigned short sAl[BM1 * BK];
    __shared__ unsigned short sBh[BN1 * BK];  // 4KB
    __shared__ unsigned short sBl[BN1 * BK];

    const int tid = threadIdx.x, wave = tid >> 6, lane = tid & 63;
    const int b0 = blockIdx.x * BM1, n0 = blockIdx.y * BN1;
    const int wm = (wave & 1) * 64, wn = (wave >> 1) * 32;
    const int row16 = lane & 15, quad = lane >> 4;

    f32x4 acc[4][2];
    #pragma unroll
    for (int i = 0; i < 4; i++)
        #pragma unroll
        for (int j = 0; j < 2; j++) acc[i][j] = (f32x4){0.f, 0.f, 0.f, 0.f};

    for (int k0 = 0; k0 < NN; k0 += BK) {
        #pragma unroll
        for (int c = 0; c < 2; ++c) {          // A tiles: 8 chunks of 1KB
            int o = (wave * 2 + c) * 1024 + lane * 16;   // byte offset in tile
            int row = o >> 6, colb = o & 63;
            size_t g = (size_t)(b0 + row) * NN + k0 + (colb >> 1);
            gload16(&Xh[g], (char*)sAh + o);
            gload16(&Xl[g], (char*)sAl + o);
        }
        {                                       // B tiles: 4 chunks of 1KB
            int o = wave * 1024 + lane * 16;
            int nrow = o >> 6, colb = o & 63;
            size_t g = (size_t)(n0 + nrow) * NN + k0 + (colb >> 1);
            gload16(&Ph[g], (char*)sBh + o);
            gload16(&Pl[g], (char*)sBl + o);
        }
        __syncthreads();
        short8 a[4], bh[2], bl[2];
        #pragma unroll
        for (int j = 0; j < 2; ++j) {
            int off = (wn + j * 16 + row16) * 64 + quad * 16;
            bh[j] = *(const short8*)((const char*)sBh + off);
            bl[j] = *(const short8*)((const char*)sBl + off);
        }
        #pragma unroll
        for (int i = 0; i < 4; ++i)
            a[i] = *(const short8*)((const char*)sAh + (wm + i * 16 + row16) * 64 + quad * 16);
        #pragma unroll
        for (int i = 0; i < 4; ++i)
            #pragma unroll
            for (int j = 0; j < 2; ++j) {
                acc[i][j] = __builtin_amdgcn_mfma_f32_16x16x32_bf16(a[i], bh[j], acc[i][j], 0, 0, 0);
                acc[i][j] = __builtin_amdgcn_mfma_f32_16x16x32_bf16(a[i], bl[j], acc[i][j], 0, 0, 0);
            }
        #pragma unroll
        for (int i = 0; i < 4; ++i)
            a[i] = *(const short8*)((const char*)sAl + (wm + i * 16 + row16) * 64 + quad * 16);
        #pragma unroll
        for (int i = 0; i < 4; ++i)
            #pragma unroll
            for (int j = 0; j < 2; ++j)
                acc[i][j] = __builtin_amdgcn_mfma_f32_16x16x32_bf16(a[i], bh[j], acc[i][j], 0, 0, 0);
        __syncthreads();
    }
    #pragma unroll
    for (int i = 0; i < 4; ++i)
        #pragma unroll
        for (int j = 0; j < 2; ++j)
            #pragma unroll
            for (int r = 0; r < 4; ++r) {
                int gm = b0 + wm + i * 16 + quad * 4 + r;
                int gn = n0 + wn + j * 16 + row16;
                size_t idx = (size_t)gm * NM + gn;
                float v = acc[i][j][r] - y[idx];
                unsigned short h = f2bf(v);
                Rth[idx] = h;
                Rtl[idx] = f2bf(v - bf2f(h));
            }
}

// ---- fused GEMM2 + exact top-50 select + soft-threshold update ----
// One block = 16 batch rows x full N=1024. V never exists in memory.
// LDS 16.5 KB, disjoint lifetimes:
//   [0,16K):  Rt h(8K)+l(8K)  ->  8x2KB wave strips  ->  hist(8.4K)
#define RH_OFF 0
#define RL_OFF 8192
#define HSTRIDE 132                      // words/row: 256 bins packed 2/word + pad
#define HIST_WORDS (16 * HSTRIDE)        // 2112 words = 8448 B
#define PREF_OFF 12288                   // u32[16]
#define RK_OFF 12352                     // u32[16]

template <int FIRST>
__global__ __launch_bounds__(512, 4) void gemm2_update(
        const unsigned short* __restrict__ Rth, const unsigned short* __restrict__ Rtl,
        const unsigned short* __restrict__ Wth, const unsigned short* __restrict__ Wtl,
        const float* __restrict__ y,
        unsigned short* __restrict__ Xh, unsigned short* __restrict__ Xl,
        const float* __restrict__ gamma, const float* __restrict__ theta,
        int it, float* __restrict__ out) {
    __shared__ __align__(16) char lds[16640];
    const int tid = threadIdx.x;
    const int w = tid >> 6;          // wave 0..7
    const int lane = tid & 63;
    const int qd = lane >> 4;        // quad 0..3
    const int r16 = lane & 15;
    const int lrow = lane >> 2;      // row this lane owns in phase B/D (0..15)
    const int lq = lane & 3;         // col-quarter within wave's 128 cols
    const int gb0 = blockIdx.x * BMROW;

    // ---- stage Rt (or -y split when FIRST: X==0 -> Rt=-y) into LDS ----
    {
        const int b = tid >> 5, c = tid & 31;    // row 0..15, 8-elem chunk 0..31
        const unsigned dst = (unsigned)(b * 512 + ((c * 16) ^ ((b & 7) << 4)));
        if (FIRST) {
            float4 v0 = *reinterpret_cast<const float4*>(&y[(size_t)(gb0 + b) * NM + c * 8]);
            float4 v1 = *reinterpret_cast<const float4*>(&y[(size_t)(gb0 + b) * NM + c * 8 + 4]);
            float vv[8] = {v0.x, v0.y, v0.z, v0.w, v1.x, v1.y, v1.z, v1.w};
            short8 hh, ll;
            #pragma unroll
            for (int e = 0; e < 8; ++e) {
                float v = -vv[e];
                unsigned short h = f2bf(v);
                hh[e] = (short)h;
                ll[e] = (short)f2bf(v - bf2f(h));
            }
            *(short8*)(lds + RH_OFF + dst) = hh;
            *(short8*)(lds + RL_OFF + dst) = ll;
        } else {
            size_t g = (size_t)(gb0 + b) * NM + c * 8;
            *(short8*)(lds + RH_OFF + dst) = *(const short8*)(Rth + g);
            *(short8*)(lds + RL_OFF + dst) = *(const short8*)(Rtl + g);
        }
    }
    __syncthreads();   // B1: Rt staged

    // ---- GEMM2: acc2[b,n] = sum_m Rt[b,m]*W[m,n]  (K = 256) ----
    const size_t wn0 = (size_t)(w * 128 + r16) * NM + qd * 8;
    f32x4 acc2[8];
    #pragma unroll
    for (int j = 0; j < 8; ++j) acc2[j] = (f32x4){0.f, 0.f, 0.f, 0.f};

    #pragma unroll 2
    for (int k = 0; k < 8; ++k) {
        const unsigned mo = ((unsigned)(k * 64 + qd * 16)) ^ ((unsigned)((r16 & 7) << 4));
        short8 ah = *(const short8*)(lds + RH_OFF + r16 * 512 + mo);
        short8 al = *(const short8*)(lds + RL_OFF + r16 * 512 + mo);
        #pragma unroll
        for (int jp = 0; jp < 4; ++jp) {
            const int j0 = 2 * jp, j1 = 2 * jp + 1;
            short8 wh0 = *(const short8*)(Wth + wn0 + j0 * 4096 + k * 32);
            short8 wl0 = *(const short8*)(Wtl + wn0 + j0 * 4096 + k * 32);
            short8 wh1 = *(const short8*)(Wth + wn0 + j1 * 4096 + k * 32);
            short8 wl1 = *(const short8*)(Wtl + wn0 + j1 * 4096 + k * 32);
            acc2[j0] = __builtin_amdgcn_mfma_f32_16x16x32_bf16(ah, wh0, acc2[j0], 0, 0, 0);
            acc2[j0] = __builtin_amdgcn_mfma_f32_16x16x32_bf16(ah, wl0, acc2[j0], 0, 0, 0);
            acc2[j0] = __builtin_amdgcn_mfma_f32_16x16x32_bf16(al, wh0, acc2[j0], 0, 0, 0);
            acc2[j1] = __builtin_amdgcn_mfma_f32_16x16x32_bf16(ah, wh1, acc2[j1], 0, 0, 0);
            acc2[j1] = __builtin_amdgcn_mfma_f32_16x16x32_bf16(ah, wl1, acc2[j1], 0, 0, 0);
            acc2[j1] = __builtin_amdgcn_mfma_f32_16x16x32_bf16(al, wh1, acc2[j1], 0, 0, 0);
        }
    }
    __syncthreads();   // B2: Rt reads done -> region reusable for strips

    // ---- layout exchange: MFMA scatter -> row-linear, intra-wave ----
    char* strip = lds + w * 2048;      // per-wave private strip
    float v[32];   // v[i] = c at (row lrow, col w*128 + lq*32 + i)
    #pragma unroll
    for (int q = 0; q < 4; ++q) {
        #pragma unroll
        for (int e = 0; e < 2; ++e) {
            const int j = 2 * q + e;
            #pragma unroll
            for (int r = 0; r < 4; ++r) {
                const int b = qd * 4 + r;
                const unsigned sb = swzS((unsigned)(b * 128 + e * 64 + r16 * 4));
                *(float*)(strip + sb) = acc2[j][r];
            }
        }
        if (lq == q) {
            #pragma unroll
            for (int g = 0; g < 8; ++g) {
                const unsigned rb = swzS((unsigned)(lrow * 128 + g * 16));
                f32x4 t = *(const f32x4*)(strip + rb);
                v[g * 4 + 0] = t[0]; v[g * 4 + 1] = t[1];
                v[g * 4 + 2] = t[2]; v[g * 4 + 3] = t[3];
            }
        }
    }
    __syncthreads();   // B3: strips dead -> region free for hist

    // ---- phase B: v = x_old - gamma*c (xo from global X; 0 when FIRST) ----
    const float gm = gamma[it];
    const float thv = theta[it];
    const size_t xg = (size_t)(gb0 + lrow) * NN + w * 128 + lq * 32;
    if (FIRST) {
        #pragma unroll
        for (int i = 0; i < 32; ++i) v[i] = -gm * v[i];
    } else {
        #pragma unroll
        for (int g = 0; g < 4; ++g) {
            short8 xh = *(const short8*)(Xh + xg + g * 8);
            short8 xl = *(const short8*)(Xl + xg + g * 8);
            #pragma unroll
            for (int e2 = 0; e2 < 8; ++e2) {
                float xo = bf2f((unsigned short)xh[e2]) + bf2f((unsigned short)xl[e2]);
                v[g * 8 + e2] = xo - gm * v[g * 8 + e2];
            }
        }
    }

    // ---- exact per-row 50th-largest |v|: 4-pass radix histogram ----
    uint32_t* hist = (uint32_t*)lds;
    uint32_t* prefA = (uint32_t*)(lds + PREF_OFF);
    uint32_t* rkA = (uint32_t*)(lds + RK_OFF);
    #pragma unroll
    for (int i = 0; i < 5; ++i) {
        int idx = tid + i * 512;
        if (idx < HIST_WORDS) hist[idx] = 0u;
    }
    if (tid < 16) { prefA[tid] = 0u; rkA[tid] = TOPK; }
    __syncthreads();   // B4

    const int srow = w * 4 + qd;   // row scanned by this quad (w<4 only)
    #pragma unroll
    for (int pass = 0; pass < 4; ++pass) {
        const int s = (pass == 0) ? 23 : (pass == 1) ? 15 : (pass == 2) ? 7 : 0;
        const int sTop = (pass == 0) ? 31 : (pass == 1) ? 23 : (pass == 2) ? 15 : 7;
        const unsigned bmask = (pass == 3) ? 0x7Fu : 0xFFu;
        const unsigned pref = prefA[lrow];
        #pragma unroll
        for (int i = 0; i < 32; ++i) {
            unsigned u = __float_as_uint(v[i]) & 0x7FFFFFFFu;
            if ((u >> sTop) == (pref >> sTop)) {
                unsigned bin = (u >> s) & bmask;
                atomicAdd(&hist[lrow * HSTRIDE + (bin >> 1)], 1u << ((bin & 1) * 16));
            }
        }
        __syncthreads();
        if (w < 4) {   // one owner quad per row: scan is RMW on prefA/rkA
            unsigned cnt[16];
            unsigned lsum = 0;
            #pragma unroll
            for (int i = 0; i < 8; ++i) {
                unsigned wd = hist[srow * HSTRIDE + r16 * 8 + i];
                cnt[2 * i] = wd & 0xFFFFu;
                cnt[2 * i + 1] = wd >> 16;
                lsum += cnt[2 * i] + cnt[2 * i + 1];
            }
            unsigned S = lsum;
            #pragma unroll
            for (int off = 1; off < 16; off <<= 1) {
                unsigned o = (unsigned)__shfl_down((int)S, off, 16);
                if (r16 + off < 16) S += o;
            }
            const unsigned rk = rkA[srow];
            const unsigned pOld = prefA[srow];
            unsigned run = S - lsum;
            #pragma unroll
            for (int i = 15; i >= 0; --i) {
                unsigned tot = run + cnt[i];
                if (run < rk && tot >= rk) {
                    prefA[srow] = pOld | (((unsigned)(r16 * 16 + i)) << s);
                    rkA[srow] = rk - run;
                }
                run = tot;
            }
        }
        __syncthreads();
        if (pass < 3) {
            #pragma unroll
            for (int i = 0; i < 5; ++i) {
                int idx = tid + i * 512;
                if (idx < HIST_WORDS) hist[idx] = 0u;
            }
            __syncthreads();
        }
    }

    // ---- phase D: soft-threshold + exact top-k passthrough, write X' ----
    const unsigned T = prefA[lrow];
    #pragma unroll
    for (int g = 0; g < 4; ++g) {
        short8 xh, xl;
        if (!FIRST) {
            xh = *(const short8*)(Xh + xg + g * 8);   // L1/L2-hot re-read
            xl = *(const short8*)(Xl + xg + g * 8);
        }
        short8 nh, nl;
        #pragma unroll
        for (int e2 = 0; e2 < 8; ++e2) {
            const int i = g * 8 + e2;
            float xo = FIRST ? 0.0f
                             : bf2f((unsigned short)xh[e2]) + bf2f((unsigned short)xl[e2]);
            float vv = v[i];
            float th = thv / (10.0f * fabsf(xo) + 1.0f);   // theta*g(|x|), EPS=0.1
            float st = copysignf(fmaxf(fabsf(vv) - th, 0.0f), vv);
            unsigned u = __float_as_uint(vv) & 0x7FFFFFFFu;
            float outv = (u > T) ? vv : st;
            unsigned short h = f2bf(outv);
            nh[e2] = (short)h;
            nl[e2] = (short)f2bf(outv - bf2f(h));
            v[i] = outv;
        }
        *(short8*)(Xh + xg + g * 8) = nh;
        *(short8*)(Xl + xg + g * 8) = nl;
    }
    if (it == NITER - 1) {
        #pragma unroll
        for (int g = 0; g < 8; ++g) {
            float4 o4 = {v[g * 4 + 0], v[g * 4 + 1], v[g * 4 + 2], v[g * 4 + 3]};
            *reinterpret_cast<float4*>(&out[xg + g * 4]) = o4;
        }
    }
}

__global__ void tail_kernel(float* __restrict__ out) {
    if (threadIdx.x < 32) out[(size_t)NB * NN + threadIdx.x] = 0.0f;
}

extern "C" void kernel_launch(void* const* d_in, const int* in_sizes, int n_in,
                              void* d_out, int out_size, void* d_ws, size_t ws_size,
                              hipStream_t stream) {
    const float* y     = (const float*)d_in[0];
    const float* phi   = (const float*)d_in[1];
    const float* W     = (const float*)d_in[2];
    const float* gamma = (const float*)d_in[3];
    const float* theta = (const float*)d_in[4];
    float* out = (float*)d_out;

    char* ws = (char*)d_ws;
    size_t off = 0;
    unsigned short* Xh  = (unsigned short*)(ws + off); off += (size_t)NB * NN * 2;  // 32MB
    unsigned short* Xl  = (unsigned short*)(ws + off); off += (size_t)NB * NN * 2;  // 32MB
    unsigned short* Rth = (unsigned short*)(ws + off); off += (size_t)NB * NM * 2;  // 8MB
    unsigned short* Rtl = (unsigned short*)(ws + off); off += (size_t)NB * NM * 2;  // 8MB
    unsigned short* Ph  = (unsigned short*)(ws + off); off += (size_t)NM * NN * 2;  // 512KB
    unsigned short* Pl  = (unsigned short*)(ws + off); off += (size_t)NM * NN * 2;
    unsigned short* Wth = (unsigned short*)(ws + off); off += (size_t)NN * NM * 2;
    unsigned short* Wtl = (unsigned short*)(ws + off); off += (size_t)NN * NM * 2;

    split_phi_kernel<<<(NM * NN) / 256, 256, 0, stream>>>(phi, Ph, Pl);
    transpose_split_W<<<dim3(NN / 32, NM / 32), dim3(32, 8), 0, stream>>>(W, Wth, Wtl);

    // it = 0: X == 0 -> Rt = -y staged straight from y; X memsets unnecessary
    gemm2_update<1><<<NBLKS2, 512, 0, stream>>>(Rth, Rtl, Wth, Wtl, y, Xh, Xl,
                                                gamma, theta, 0, out);
    for (int it = 1; it < NITER; ++it) {
        gemm1_mfma<<<dim3(NB / BM1, NM / BN1), 256, 0, stream>>>(Xh, Xl, Ph, Pl, y, Rth, Rtl);
        gemm2_update<0><<<NBLKS2, 512, 0, stream>>>(Rth, Rtl, Wth, Wtl, y, Xh, Xl,
                                                    gamma, theta, it, out);
    }
    tail_kernel<<<1, 32, 0, stream>>>(out);
}